// Round 2
// baseline (1310.027 us; speedup 1.0000x reference)
//
#include <hip/hip_runtime.h>

// ---------------- problem constants ----------------
#define N0 262144
#define N1 32768
#define N2 4096
#define EPSBN 1e-5f

// ---------------- conv kernel ----------------
// y[m, dg*DTILE + d] (+)= sum_{t in tap group kg} sum_c x[neigh[m, kg*TAPS+t], c] * W[kg*TAPS+t, c, dg*DTILE+d]
// x = FIRST ? f32 input : relu(yprev * scale + shift)  (scale/shift in ss[0..CIN), ss[CIN..2CIN))
template<int K, int CIN, int COUT, int TAPS, int DTILE, int KG, int DG, bool FIRST>
__global__ __launch_bounds__(256) void conv_kernel(
    const float* __restrict__ xin,       // FIRST: [Nin, CIN] f32
    const float* __restrict__ yprev,     // !FIRST: [Nin, CIN] f32 raw conv out
    const float* __restrict__ ss,        // !FIRST: [2*CIN] scale, shift
    const int*   __restrict__ neigh,     // [M, K]
    const float* __restrict__ W,         // [K, CIN, COUT] f32
    float*       __restrict__ yout,      // [M, COUT]
    int M)
{
    static_assert(K == TAPS * KG, "k split");
    static_assert(COUT == DTILE * DG, "d split");
    constexpr int WSZ = TAPS * CIN * DTILE;
    __shared__ __align__(16) float Wl[WSZ];
    __shared__ float ssl[FIRST ? 4 : 2 * CIN];

    const int tid = threadIdx.x;
    const int kg = blockIdx.y, dg = blockIdx.z;

    for (int i = tid; i < WSZ; i += 256) {
        int d  = i % DTILE;
        int rc = i / DTILE;
        int c  = rc % CIN;
        int t  = rc / CIN;
        Wl[i] = W[((size_t)(kg * TAPS + t) * CIN + c) * COUT + dg * DTILE + d];
    }
    if constexpr (!FIRST) {
        for (int i = tid; i < 2 * CIN; i += 256) ssl[i] = ss[i];
    }
    __syncthreads();

    const int m = blockIdx.x * 256 + tid;
    if (m >= M) return;

    float acc[DTILE];
#pragma unroll
    for (int d = 0; d < DTILE; ++d) acc[d] = 0.f;

    const int* np = neigh + (size_t)m * K + kg * TAPS;

    for (int t = 0; t < TAPS; ++t) {
        const int idx = np[t];
        if constexpr (FIRST) {
            // CIN == 3, f32 input, no affine
            const float x0 = xin[(size_t)idx * 3 + 0];
            const float x1 = xin[(size_t)idx * 3 + 1];
            const float x2 = xin[(size_t)idx * 3 + 2];
            const float4* wp0 = (const float4*)&Wl[(t * 3 + 0) * DTILE];
            const float4* wp1 = (const float4*)&Wl[(t * 3 + 1) * DTILE];
            const float4* wp2 = (const float4*)&Wl[(t * 3 + 2) * DTILE];
#pragma unroll
            for (int d4 = 0; d4 < DTILE / 4; ++d4) {
                float4 w0 = wp0[d4], w1 = wp1[d4], w2 = wp2[d4];
                acc[4 * d4 + 0] += x0 * w0.x + x1 * w1.x + x2 * w2.x;
                acc[4 * d4 + 1] += x0 * w0.y + x1 * w1.y + x2 * w2.y;
                acc[4 * d4 + 2] += x0 * w0.z + x1 * w1.z + x2 * w2.z;
                acc[4 * d4 + 3] += x0 * w0.w + x1 * w1.w + x2 * w2.w;
            }
        } else {
            const float4* xp = (const float4*)(yprev + (size_t)idx * CIN);
#pragma unroll 1
            for (int c4 = 0; c4 < CIN; c4 += 4) {
                float4 xv = xp[c4 >> 2];
                float a0 = fmaxf(xv.x * ssl[c4 + 0] + ssl[CIN + c4 + 0], 0.f);
                float a1 = fmaxf(xv.y * ssl[c4 + 1] + ssl[CIN + c4 + 1], 0.f);
                float a2 = fmaxf(xv.z * ssl[c4 + 2] + ssl[CIN + c4 + 2], 0.f);
                float a3 = fmaxf(xv.w * ssl[c4 + 3] + ssl[CIN + c4 + 3], 0.f);
                const float4* wp0 = (const float4*)&Wl[(t * CIN + c4 + 0) * DTILE];
                const float4* wp1 = (const float4*)&Wl[(t * CIN + c4 + 1) * DTILE];
                const float4* wp2 = (const float4*)&Wl[(t * CIN + c4 + 2) * DTILE];
                const float4* wp3 = (const float4*)&Wl[(t * CIN + c4 + 3) * DTILE];
#pragma unroll
                for (int d4 = 0; d4 < DTILE / 4; ++d4) {
                    float4 w0 = wp0[d4], w1 = wp1[d4], w2 = wp2[d4], w3 = wp3[d4];
                    acc[4 * d4 + 0] += a0 * w0.x + a1 * w1.x + a2 * w2.x + a3 * w3.x;
                    acc[4 * d4 + 1] += a0 * w0.y + a1 * w1.y + a2 * w2.y + a3 * w3.y;
                    acc[4 * d4 + 2] += a0 * w0.z + a1 * w1.z + a2 * w2.z + a3 * w3.z;
                    acc[4 * d4 + 3] += a0 * w0.w + a1 * w1.w + a2 * w2.w + a3 * w3.w;
                }
            }
        }
    }

    float* yo = yout + (size_t)m * COUT + dg * DTILE;
    if constexpr (KG > 1) {
#pragma unroll
        for (int d = 0; d < DTILE; ++d) atomicAdd(&yo[d], acc[d]);
    } else {
#pragma unroll
        for (int d4 = 0; d4 < DTILE / 4; ++d4) {
            float4 v = make_float4(acc[4 * d4 + 0], acc[4 * d4 + 1], acc[4 * d4 + 2], acc[4 * d4 + 3]);
            ((float4*)yo)[d4] = v;
        }
    }
}

// ---------------- stats (+fused finalize) ----------------
// sums[0..C): sum, sums[C..2C): sumsq. Last block computes ss_out[0..C)=scale, [C..2C)=shift.
template<int C, int R>
__global__ void stats_kernel(const float* __restrict__ y, int M,
                             const float* __restrict__ gamma_, const float* __restrict__ beta_,
                             float* __restrict__ sums, int* __restrict__ counter,
                             float* __restrict__ ss_out)
{
    __shared__ float ls[R][C];
    __shared__ float lq[R][C];
    __shared__ int lastflag;

    const int c = threadIdx.x;   // [0, C)
    const int ty = threadIdx.y;  // [0, R)

    float s = 0.f, q = 0.f;
    for (int r = blockIdx.x * R + ty; r < M; r += gridDim.x * R) {
        float v = y[(size_t)r * C + c];
        s += v;
        q += v * v;
    }
    ls[ty][c] = s; lq[ty][c] = q;
    __syncthreads();
    if (ty == 0) {
#pragma unroll
        for (int r = 1; r < R; ++r) { s += ls[r][c]; q += lq[r][c]; }
        atomicAdd(&sums[c], s);
        atomicAdd(&sums[C + c], q);
    }
    __syncthreads();
    if (c == 0 && ty == 0) {
        __threadfence();
        int p = __hip_atomic_fetch_add(counter, 1, __ATOMIC_ACQ_REL, __HIP_MEMORY_SCOPE_AGENT);
        lastflag = (p == (int)gridDim.x - 1) ? 1 : 0;
    }
    __syncthreads();
    if (lastflag && ty == 0) {
        float S = __hip_atomic_load(&sums[c],     __ATOMIC_RELAXED, __HIP_MEMORY_SCOPE_AGENT);
        float Q = __hip_atomic_load(&sums[C + c], __ATOMIC_RELAXED, __HIP_MEMORY_SCOPE_AGENT);
        float mu  = S / (float)M;
        float var = fmaxf(Q / (float)M - mu * mu, 0.f);
        float scale = gamma_[c] / sqrtf(var + EPSBN);
        float shift = beta_[c] - mu * scale;
        ss_out[c] = scale;
        ss_out[C + c] = shift;
    }
}

// ---------------- final write ----------------
__global__ void writeout_kernel(const float* __restrict__ y, const float* __restrict__ ss,
                                float* __restrict__ out, int total)
{
    int i = (blockIdx.x * blockDim.x + threadIdx.x) * 4;
    if (i >= total) return;
    float4 v = *(const float4*)(y + i);
    int c = i % 96;
    float4 o;
    o.x = fmaxf(v.x * ss[c + 0] + ss[96 + c + 0], 0.f);
    o.y = fmaxf(v.y * ss[c + 1] + ss[96 + c + 1], 0.f);
    o.z = fmaxf(v.z * ss[c + 2] + ss[96 + c + 2], 0.f);
    o.w = fmaxf(v.w * ss[c + 3] + ss[96 + c + 3], 0.f);
    *(float4*)(out + i) = o;
}

// ---------------- host ----------------
extern "C" void kernel_launch(void* const* d_in, const int* in_sizes, int n_in,
                              void* d_out, int out_size, void* d_ws, size_t ws_size,
                              hipStream_t stream)
{
    const float* data   = (const float*)d_in[0];
    const int*   neigh0 = (const int*)d_in[1];
    const int*   child0 = (const int*)d_in[2];
    const int*   neigh1 = (const int*)d_in[3];
    const int*   child1 = (const int*)d_in[4];
    const int*   neigh2 = (const int*)d_in[5];
    const float* w0  = (const float*)d_in[6];
    const float* g0  = (const float*)d_in[7];
    const float* b0  = (const float*)d_in[8];
    const float* wd0 = (const float*)d_in[9];
    const float* gd0 = (const float*)d_in[10];
    const float* bd0 = (const float*)d_in[11];
    const float* w1  = (const float*)d_in[12];
    const float* g1  = (const float*)d_in[13];
    const float* b1  = (const float*)d_in[14];
    const float* wd1 = (const float*)d_in[15];
    const float* gd1 = (const float*)d_in[16];
    const float* bd1 = (const float*)d_in[17];
    const float* wp  = (const float*)d_in[18];
    const float* gp  = (const float*)d_in[19];
    const float* bp  = (const float*)d_in[20];
    float* out = (float*)d_out;

    // workspace layout (floats)
    float* wsf = (float*)d_ws;
    int*   counters = (int*)d_ws;              // 5 ints in first 64B
    float* sums0 = wsf + 16;                   // 48
    float* sums1 = wsf + 64;                   // 96
    float* sums2 = wsf + 160;                  // 96
    float* sums3 = wsf + 256;                  // 192
    float* sums4 = wsf + 448;                  // 192 (end 640)
    float* ss0 = wsf + 640;                    // 48
    float* ss1 = wsf + 688;                    // 96
    float* ss2 = wsf + 784;                    // 96
    float* ss3 = wsf + 880;                    // 192
    float* ss4 = wsf + 1072;                   // 192 (end 1264, pad to 1280)
    float* y1 = wsf + 1280;                    // N1*48 = 1572864
    float* y2 = y1 + (size_t)N1 * 48;          // 1572864
    float* y3 = y2 + (size_t)N1 * 48;          // N2*96 = 393216
    float* y4 = y3 + (size_t)N2 * 96;          // 393216  (zero region ends here)
    float* y0 = y4 + (size_t)N2 * 96;          // N0*24 = 6291456 (not zeroed)

    const size_t zero_bytes = (size_t)(1280 + 2 * (size_t)N1 * 48 + 2 * (size_t)N2 * 96) * 4;
    hipMemsetAsync(d_ws, 0, zero_bytes, stream);

    // stage A: data[N0,3] -> y0[N0,24], direct write
    conv_kernel<27, 3, 24, 27, 24, 1, 1, true>
        <<<dim3(N0 / 256, 1, 1), 256, 0, stream>>>(data, nullptr, nullptr, neigh0, w0, y0, N0);
    stats_kernel<24, 8><<<512, dim3(24, 8), 0, stream>>>(y0, N0, g0, b0, sums0, &counters[0], ss0);

    // stage B: x0[N0,24] -> y1[N1,48], k-split 2
    conv_kernel<8, 24, 48, 4, 24, 2, 2, false>
        <<<dim3(N1 / 256, 2, 2), 256, 0, stream>>>(nullptr, y0, ss0, child0, wd0, y1, N1);
    stats_kernel<48, 8><<<128, dim3(48, 8), 0, stream>>>(y1, N1, gd0, bd0, sums1, &counters[1], ss1);

    // stage C: x1[N1,48] -> y2[N1,48], k-split 3
    conv_kernel<27, 48, 48, 9, 24, 3, 2, false>
        <<<dim3(N1 / 256, 3, 2), 256, 0, stream>>>(nullptr, y1, ss1, neigh1, w1, y2, N1);
    stats_kernel<48, 8><<<128, dim3(48, 8), 0, stream>>>(y2, N1, g1, b1, sums2, &counters[2], ss2);

    // stage D: x2[N1,48] -> y3[N2,96], k-split 8
    conv_kernel<8, 48, 96, 1, 24, 8, 4, false>
        <<<dim3(N2 / 256, 8, 4), 256, 0, stream>>>(nullptr, y2, ss2, child1, wd1, y3, N2);
    stats_kernel<96, 4><<<64, dim3(96, 4), 0, stream>>>(y3, N2, gd1, bd1, sums3, &counters[3], ss3);

    // stage E: x3[N2,96] -> y4[N2,96], k-split 9
    conv_kernel<27, 96, 96, 3, 24, 9, 4, false>
        <<<dim3(N2 / 256, 9, 4), 256, 0, stream>>>(nullptr, y3, ss3, neigh2, wp, y4, N2);
    stats_kernel<96, 4><<<64, dim3(96, 4), 0, stream>>>(y4, N2, gp, bp, sums4, &counters[4], ss4);

    // final normalize + relu + f32 out
    writeout_kernel<<<(N2 * 96 / 4 + 255) / 256, 256, 0, stream>>>(y4, ss4, out, N2 * 96);

    (void)in_sizes; (void)n_in; (void)out_size; (void)ws_size;
}

// Round 3
// 555.802 us; speedup vs baseline: 2.3570x; 2.3570x over previous
//
#include <hip/hip_runtime.h>

// ---------------- problem constants ----------------
#define N0 262144
#define N1 32768
#define N2 4096
#define EPSBN 1e-5f

// ---------------- conv kernel ----------------
// Partial output p=kg: ypart[kg][m, dg*DTILE+d] = sum_{t in tap group kg} sum_c x[...] * W[...]
// x = FIRST ? f32 input : relu(yprev * scale + shift)
template<int K, int CIN, int COUT, int TAPS, int DTILE, int KG, int DG, bool FIRST>
__global__ __launch_bounds__(256) void conv_kernel(
    const float* __restrict__ xin,       // FIRST: [Nin, CIN] f32
    const float* __restrict__ yprev,     // !FIRST: [Nin, CIN] f32 raw conv out
    const float* __restrict__ ss,        // !FIRST: [2*CIN] scale, shift
    const int*   __restrict__ neigh,     // [M, K]
    const float* __restrict__ W,         // [K, CIN, COUT] f32
    float*       __restrict__ yout,      // KG==1: [M,COUT]; KG>1: partial base, stride ystride
    size_t       ystride,                // elements between partial buffers
    int M)
{
    static_assert(K == TAPS * KG, "k split");
    static_assert(COUT == DTILE * DG, "d split");
    constexpr int WSZ = TAPS * CIN * DTILE;
    __shared__ __align__(16) float Wl[WSZ];
    __shared__ float ssl[FIRST ? 4 : 2 * CIN];

    const int tid = threadIdx.x;
    const int kg = blockIdx.y, dg = blockIdx.z;

    for (int i = tid; i < WSZ; i += 256) {
        int d  = i % DTILE;
        int rc = i / DTILE;
        int c  = rc % CIN;
        int t  = rc / CIN;
        Wl[i] = W[((size_t)(kg * TAPS + t) * CIN + c) * COUT + dg * DTILE + d];
    }
    if constexpr (!FIRST) {
        for (int i = tid; i < 2 * CIN; i += 256) ssl[i] = ss[i];
    }
    __syncthreads();

    const int m = blockIdx.x * 256 + tid;
    if (m >= M) return;

    float acc[DTILE];
#pragma unroll
    for (int d = 0; d < DTILE; ++d) acc[d] = 0.f;

    // prefetch all tap indices (independent of gather loads)
    int idxs[TAPS];
    const int* np = neigh + (size_t)m * K + kg * TAPS;
#pragma unroll
    for (int t = 0; t < TAPS; ++t) idxs[t] = np[t];

    if constexpr (FIRST) {
        // CIN == 3, f32 input, no affine
#pragma unroll 3
        for (int t = 0; t < TAPS; ++t) {
            const float* xp = xin + (size_t)idxs[t] * 3;
            const float x0 = xp[0], x1 = xp[1], x2 = xp[2];
            const float4* wp0 = (const float4*)&Wl[(t * 3 + 0) * DTILE];
            const float4* wp1 = (const float4*)&Wl[(t * 3 + 1) * DTILE];
            const float4* wp2 = (const float4*)&Wl[(t * 3 + 2) * DTILE];
#pragma unroll
            for (int d4 = 0; d4 < DTILE / 4; ++d4) {
                float4 w0 = wp0[d4], w1 = wp1[d4], w2 = wp2[d4];
                acc[4 * d4 + 0] += x0 * w0.x + x1 * w1.x + x2 * w2.x;
                acc[4 * d4 + 1] += x0 * w0.y + x1 * w1.y + x2 * w2.y;
                acc[4 * d4 + 2] += x0 * w0.z + x1 * w1.z + x2 * w2.z;
                acc[4 * d4 + 3] += x0 * w0.w + x1 * w1.w + x2 * w2.w;
            }
        }
    } else {
        // batch all chunk loads into registers BEFORE use -> many outstanding loads
        constexpr int CHUNK = (CIN <= 48) ? CIN : 32;
        for (int t = 0; t < TAPS; ++t) {
            const float4* xp = (const float4*)(yprev + (size_t)idxs[t] * CIN);
#pragma unroll
            for (int cc = 0; cc < CIN / CHUNK; ++cc) {
                float4 xv[CHUNK / 4];
#pragma unroll
                for (int j = 0; j < CHUNK / 4; ++j) xv[j] = xp[cc * (CHUNK / 4) + j];
#pragma unroll
                for (int j = 0; j < CHUNK / 4; ++j) {
                    const int c4 = cc * CHUNK + 4 * j;
                    const float a0 = fmaxf(xv[j].x * ssl[c4 + 0] + ssl[CIN + c4 + 0], 0.f);
                    const float a1 = fmaxf(xv[j].y * ssl[c4 + 1] + ssl[CIN + c4 + 1], 0.f);
                    const float a2 = fmaxf(xv[j].z * ssl[c4 + 2] + ssl[CIN + c4 + 2], 0.f);
                    const float a3 = fmaxf(xv[j].w * ssl[c4 + 3] + ssl[CIN + c4 + 3], 0.f);
                    const float4* wp0 = (const float4*)&Wl[(t * CIN + c4 + 0) * DTILE];
                    const float4* wp1 = (const float4*)&Wl[(t * CIN + c4 + 1) * DTILE];
                    const float4* wp2 = (const float4*)&Wl[(t * CIN + c4 + 2) * DTILE];
                    const float4* wp3 = (const float4*)&Wl[(t * CIN + c4 + 3) * DTILE];
#pragma unroll
                    for (int d4 = 0; d4 < DTILE / 4; ++d4) {
                        float4 w0 = wp0[d4], w1 = wp1[d4], w2 = wp2[d4], w3 = wp3[d4];
                        acc[4 * d4 + 0] += a0 * w0.x + a1 * w1.x + a2 * w2.x + a3 * w3.x;
                        acc[4 * d4 + 1] += a0 * w0.y + a1 * w1.y + a2 * w2.y + a3 * w3.y;
                        acc[4 * d4 + 2] += a0 * w0.z + a1 * w1.z + a2 * w2.z + a3 * w3.z;
                        acc[4 * d4 + 3] += a0 * w0.w + a1 * w1.w + a2 * w2.w + a3 * w3.w;
                    }
                }
            }
        }
    }

    float* yo = (KG > 1)
        ? yout + (size_t)kg * ystride + (size_t)m * COUT + dg * DTILE
        : yout + (size_t)m * COUT + dg * DTILE;
#pragma unroll
    for (int d4 = 0; d4 < DTILE / 4; ++d4) {
        ((float4*)yo)[d4] = make_float4(acc[4 * d4 + 0], acc[4 * d4 + 1],
                                        acc[4 * d4 + 2], acc[4 * d4 + 3]);
    }
}

// ---------------- stats: sum P partials -> yfull, column sum/sumsq, fused finalize ----------------
template<int C, int R, int P, bool WRITE_Y>
__global__ void stats_kernel(const float* __restrict__ part, size_t pstride,
                             float* __restrict__ yfull, int M,
                             const float* __restrict__ gamma_, const float* __restrict__ beta_,
                             float* __restrict__ sums, int* __restrict__ counter,
                             float* __restrict__ ss_out)
{
    __shared__ float ls[R][C];
    __shared__ float lq[R][C];
    __shared__ int lastflag;

    const int c = threadIdx.x;   // [0, C)
    const int ty = threadIdx.y;  // [0, R)

    float s = 0.f, q = 0.f;
    for (int r = blockIdx.x * R + ty; r < M; r += gridDim.x * R) {
        const size_t off = (size_t)r * C + c;
        float v = 0.f;
#pragma unroll
        for (int p = 0; p < P; ++p) v += part[(size_t)p * pstride + off];
        if constexpr (WRITE_Y) yfull[off] = v;
        s += v;
        q += v * v;
    }
    ls[ty][c] = s; lq[ty][c] = q;
    __syncthreads();
    if (ty == 0) {
#pragma unroll
        for (int r = 1; r < R; ++r) { s += ls[r][c]; q += lq[r][c]; }
        atomicAdd(&sums[c], s);
        atomicAdd(&sums[C + c], q);
    }
    __syncthreads();
    if (c == 0 && ty == 0) {
        __threadfence();
        int p = __hip_atomic_fetch_add(counter, 1, __ATOMIC_ACQ_REL, __HIP_MEMORY_SCOPE_AGENT);
        lastflag = (p == (int)gridDim.x - 1) ? 1 : 0;
    }
    __syncthreads();
    if (lastflag && ty == 0) {
        float S = __hip_atomic_load(&sums[c],     __ATOMIC_RELAXED, __HIP_MEMORY_SCOPE_AGENT);
        float Q = __hip_atomic_load(&sums[C + c], __ATOMIC_RELAXED, __HIP_MEMORY_SCOPE_AGENT);
        float mu  = S / (float)M;
        float var = fmaxf(Q / (float)M - mu * mu, 0.f);
        float scale = gamma_[c] / sqrtf(var + EPSBN);
        float shift = beta_[c] - mu * scale;
        ss_out[c] = scale;
        ss_out[C + c] = shift;
    }
}

// ---------------- final write ----------------
__global__ void writeout_kernel(const float* __restrict__ y, const float* __restrict__ ss,
                                float* __restrict__ out, int total)
{
    int i = (blockIdx.x * blockDim.x + threadIdx.x) * 4;
    if (i >= total) return;
    float4 v = *(const float4*)(y + i);
    int c = i % 96;
    float4 o;
    o.x = fmaxf(v.x * ss[c + 0] + ss[96 + c + 0], 0.f);
    o.y = fmaxf(v.y * ss[c + 1] + ss[96 + c + 1], 0.f);
    o.z = fmaxf(v.z * ss[c + 2] + ss[96 + c + 2], 0.f);
    o.w = fmaxf(v.w * ss[c + 3] + ss[96 + c + 3], 0.f);
    *(float4*)(out + i) = o;
}

// ---------------- host ----------------
extern "C" void kernel_launch(void* const* d_in, const int* in_sizes, int n_in,
                              void* d_out, int out_size, void* d_ws, size_t ws_size,
                              hipStream_t stream)
{
    const float* data   = (const float*)d_in[0];
    const int*   neigh0 = (const int*)d_in[1];
    const int*   child0 = (const int*)d_in[2];
    const int*   neigh1 = (const int*)d_in[3];
    const int*   child1 = (const int*)d_in[4];
    const int*   neigh2 = (const int*)d_in[5];
    const float* w0  = (const float*)d_in[6];
    const float* g0  = (const float*)d_in[7];
    const float* b0  = (const float*)d_in[8];
    const float* wd0 = (const float*)d_in[9];
    const float* gd0 = (const float*)d_in[10];
    const float* bd0 = (const float*)d_in[11];
    const float* w1  = (const float*)d_in[12];
    const float* g1  = (const float*)d_in[13];
    const float* b1  = (const float*)d_in[14];
    const float* wd1 = (const float*)d_in[15];
    const float* gd1 = (const float*)d_in[16];
    const float* bd1 = (const float*)d_in[17];
    const float* wp  = (const float*)d_in[18];
    const float* gp  = (const float*)d_in[19];
    const float* bp  = (const float*)d_in[20];
    float* out = (float*)d_out;

    // workspace layout (floats)
    float* wsf = (float*)d_ws;
    int*   counters = (int*)d_ws;              // 5 ints in first 64B
    float* sums0 = wsf + 16;                   // 48
    float* sums1 = wsf + 64;                   // 96
    float* sums2 = wsf + 160;                  // 96
    float* sums3 = wsf + 256;                  // 192
    float* sums4 = wsf + 448;                  // 192 (end 640)
    float* ss0 = wsf + 640;                    // 48
    float* ss1 = wsf + 688;                    // 96
    float* ss2 = wsf + 784;                    // 96
    float* ss3 = wsf + 880;                    // 192
    float* ss4 = wsf + 1072;                   // 192 (end 1264, pad 1280)
    float* y0 = wsf + 1280;                    // N0*24 = 6291456
    float* y1 = y0 + (size_t)N0 * 24;          // N1*48 = 1572864
    float* y2 = y1 + (size_t)N1 * 48;          // 1572864
    float* y3 = y2 + (size_t)N1 * 48;          // N2*96 = 393216
    float* y4 = y3 + (size_t)N2 * 96;          // 393216
    float* pscratch = y4 + (size_t)N2 * 96;    // max 3*N1*48 = 4718592 floats

    // only counters + sums need zeroing (5 KB)
    hipMemsetAsync(d_ws, 0, 1280 * sizeof(float), stream);

    const size_t s1 = (size_t)N1 * 48;  // partial stride, stages B/C
    const size_t s2 = (size_t)N2 * 96;  // partial stride, stages D/E

    // stage A: data[N0,3] -> y0[N0,24], direct write
    conv_kernel<27, 3, 24, 27, 24, 1, 1, true>
        <<<dim3(N0 / 256, 1, 1), 256, 0, stream>>>(data, nullptr, nullptr, neigh0, w0, y0, 0, N0);
    stats_kernel<24, 8, 1, false><<<512, dim3(24, 8), 0, stream>>>(y0, 0, nullptr, N0, g0, b0, sums0, &counters[0], ss0);

    // stage B: x0[N0,24] -> y1[N1,48], k-split 2 -> partials
    conv_kernel<8, 24, 48, 4, 24, 2, 2, false>
        <<<dim3(N1 / 256, 2, 2), 256, 0, stream>>>(nullptr, y0, ss0, child0, wd0, pscratch, s1, N1);
    stats_kernel<48, 8, 2, true><<<128, dim3(48, 8), 0, stream>>>(pscratch, s1, y1, N1, gd0, bd0, sums1, &counters[1], ss1);

    // stage C: x1[N1,48] -> y2[N1,48], k-split 3 -> partials
    conv_kernel<27, 48, 48, 9, 24, 3, 2, false>
        <<<dim3(N1 / 256, 3, 2), 256, 0, stream>>>(nullptr, y1, ss1, neigh1, w1, pscratch, s1, N1);
    stats_kernel<48, 8, 3, true><<<128, dim3(48, 8), 0, stream>>>(pscratch, s1, y2, N1, g1, b1, sums2, &counters[2], ss2);

    // stage D: x2[N1,48] -> y3[N2,96], k-split 8 -> partials
    conv_kernel<8, 48, 96, 1, 24, 8, 4, false>
        <<<dim3(N2 / 256, 8, 4), 256, 0, stream>>>(nullptr, y2, ss2, child1, wd1, pscratch, s2, N2);
    stats_kernel<96, 4, 8, true><<<64, dim3(96, 4), 0, stream>>>(pscratch, s2, y3, N2, gd1, bd1, sums3, &counters[3], ss3);

    // stage E: x3[N2,96] -> y4[N2,96], k-split 9 -> partials
    conv_kernel<27, 96, 96, 3, 24, 9, 4, false>
        <<<dim3(N2 / 256, 9, 4), 256, 0, stream>>>(nullptr, y3, ss3, neigh2, wp, pscratch, s2, N2);
    stats_kernel<96, 4, 9, true><<<64, dim3(96, 4), 0, stream>>>(pscratch, s2, y4, N2, gp, bp, sums4, &counters[4], ss4);

    // final normalize + relu + f32 out
    writeout_kernel<<<(N2 * 96 / 4 + 255) / 256, 256, 0, stream>>>(y4, ss4, out, N2 * 96);

    (void)in_sizes; (void)n_in; (void)out_size; (void)ws_size;
}

// Round 4
// 443.381 us; speedup vs baseline: 2.9546x; 1.2536x over previous
//
#include <hip/hip_runtime.h>

// ---------------- problem constants ----------------
#define N0 262144
#define N1 32768
#define N2 4096
#define EPSBN 1e-5f

// ---------------- conv kernel (pure gather-GEMM; input already activated) ----------------
// partial p=kg: ypart[kg][m, dg*DTILE+d] = sum_{t in tap group kg} sum_c x[neigh[m,kg*TAPS+t], c] * W[kg*TAPS+t, c, dg*DTILE+d]
template<int K, int CIN, int COUT, int TAPS, int DTILE, int KG, int DG, bool FIRST>
__global__ __launch_bounds__(256) void conv_kernel(
    const float* __restrict__ x,         // [Nin, CIN] (FIRST: raw input, CIN=3)
    const int*   __restrict__ neigh,     // [M, K]
    const float* __restrict__ W,         // [K, CIN, COUT] f32
    float*       __restrict__ yout,      // KG==1: [M,COUT]; KG>1: partial base
    size_t       ystride,                // elements between partial buffers
    int M)
{
    static_assert(K == TAPS * KG, "k split");
    static_assert(COUT == DTILE * DG, "d split");
    constexpr int WSZ = TAPS * CIN * DTILE;
    __shared__ __align__(16) float Wl[WSZ];

    const int tid = threadIdx.x;
    const int kg = blockIdx.y, dg = blockIdx.z;

    // vectorized float4 weight staging: Wl[(t*CIN+c)*DTILE + d]
    for (int i4 = tid; i4 < WSZ / 4; i4 += 256) {
        const int d4 = i4 % (DTILE / 4);
        const int rc = i4 / (DTILE / 4);            // t*CIN + c
        const float4* src = (const float4*)(W + ((size_t)kg * TAPS * CIN + rc) * COUT + dg * DTILE);
        ((float4*)Wl)[i4] = src[d4];
    }
    __syncthreads();

    const int m = blockIdx.x * 256 + tid;
    if (m >= M) return;

    float acc[DTILE];
#pragma unroll
    for (int d = 0; d < DTILE; ++d) acc[d] = 0.f;

    int idxs[TAPS];
    const int* np = neigh + (size_t)m * K + kg * TAPS;
#pragma unroll
    for (int t = 0; t < TAPS; ++t) idxs[t] = np[t];

    if constexpr (FIRST) {
        // CIN == 3: scalar gathers, batch 9 taps of loads ahead of use
#pragma unroll
        for (int tg = 0; tg < TAPS; tg += 9) {
            float xs[9][3];
#pragma unroll
            for (int u = 0; u < 9; ++u) {
                const float* xp = x + (size_t)idxs[tg + u] * 3;
                xs[u][0] = xp[0]; xs[u][1] = xp[1]; xs[u][2] = xp[2];
            }
#pragma unroll
            for (int u = 0; u < 9; ++u) {
                const int t = tg + u;
#pragma unroll
                for (int c = 0; c < 3; ++c) {
                    const float a = xs[u][c];
                    const float4* wrow = (const float4*)&Wl[(t * 3 + c) * DTILE];
#pragma unroll
                    for (int d4 = 0; d4 < DTILE / 4; ++d4) {
                        float4 w = wrow[d4];
                        acc[4 * d4 + 0] += a * w.x;
                        acc[4 * d4 + 1] += a * w.y;
                        acc[4 * d4 + 2] += a * w.z;
                        acc[4 * d4 + 3] += a * w.w;
                    }
                }
            }
        }
    } else {
        constexpr int CHUNK = 24;   // 6 float4 staging regs
        for (int t = 0; t < TAPS; ++t) {
            const float4* xp = (const float4*)(x + (size_t)idxs[t] * CIN);
#pragma unroll
            for (int cc = 0; cc < CIN / CHUNK; ++cc) {
                float4 xv[CHUNK / 4];
#pragma unroll
                for (int j = 0; j < CHUNK / 4; ++j) xv[j] = xp[cc * (CHUNK / 4) + j];
#pragma unroll
                for (int j = 0; j < CHUNK / 4; ++j) {
                    const float a4[4] = {xv[j].x, xv[j].y, xv[j].z, xv[j].w};
#pragma unroll
                    for (int e = 0; e < 4; ++e) {
                        const int c = cc * CHUNK + 4 * j + e;
                        const float a = a4[e];
                        const float4* wrow = (const float4*)&Wl[(t * CIN + c) * DTILE];
#pragma unroll
                        for (int d4 = 0; d4 < DTILE / 4; ++d4) {
                            float4 w = wrow[d4];
                            acc[4 * d4 + 0] += a * w.x;
                            acc[4 * d4 + 1] += a * w.y;
                            acc[4 * d4 + 2] += a * w.z;
                            acc[4 * d4 + 3] += a * w.w;
                        }
                    }
                }
            }
        }
    }

    float* yo = (KG > 1)
        ? yout + (size_t)kg * ystride + (size_t)m * COUT + dg * DTILE
        : yout + (size_t)m * COUT + dg * DTILE;
#pragma unroll
    for (int d4 = 0; d4 < DTILE / 4; ++d4) {
        ((float4*)yo)[d4] = make_float4(acc[4 * d4 + 0], acc[4 * d4 + 1],
                                        acc[4 * d4 + 2], acc[4 * d4 + 3]);
    }
}

// ---------------- stats: sum P partials -> yfull, column sum/sumsq, fused finalize ----------------
template<int C, int R, int P, bool WRITE_Y>
__global__ void stats_kernel(const float* __restrict__ part, size_t pstride,
                             float* __restrict__ yfull, int M,
                             const float* __restrict__ gamma_, const float* __restrict__ beta_,
                             float* __restrict__ sums, int* __restrict__ counter,
                             float* __restrict__ ss_out)
{
    __shared__ float ls[R][C];
    __shared__ float lq[R][C];
    __shared__ int lastflag;

    const int c = threadIdx.x;   // [0, C)
    const int ty = threadIdx.y;  // [0, R)

    float s = 0.f, q = 0.f;
    for (int r = blockIdx.x * R + ty; r < M; r += gridDim.x * R) {
        const size_t off = (size_t)r * C + c;
        float v = 0.f;
#pragma unroll
        for (int p = 0; p < P; ++p) v += part[(size_t)p * pstride + off];
        if constexpr (WRITE_Y) yfull[off] = v;
        s += v;
        q += v * v;
    }
    ls[ty][c] = s; lq[ty][c] = q;
    __syncthreads();
    if (ty == 0) {
#pragma unroll
        for (int r = 1; r < R; ++r) { s += ls[r][c]; q += lq[r][c]; }
        atomicAdd(&sums[c], s);
        atomicAdd(&sums[C + c], q);
    }
    __syncthreads();
    if (c == 0 && ty == 0) {
        __threadfence();
        int p = __hip_atomic_fetch_add(counter, 1, __ATOMIC_ACQ_REL, __HIP_MEMORY_SCOPE_AGENT);
        lastflag = (p == (int)gridDim.x - 1) ? 1 : 0;
    }
    __syncthreads();
    if (lastflag && ty == 0) {
        float S = __hip_atomic_load(&sums[c],     __ATOMIC_RELAXED, __HIP_MEMORY_SCOPE_AGENT);
        float Q = __hip_atomic_load(&sums[C + c], __ATOMIC_RELAXED, __HIP_MEMORY_SCOPE_AGENT);
        float mu  = S / (float)M;
        float var = fmaxf(Q / (float)M - mu * mu, 0.f);
        float scale = gamma_[c] / sqrtf(var + EPSBN);
        float shift = beta_[c] - mu * scale;
        ss_out[c] = scale;
        ss_out[C + c] = shift;
    }
}

// ---------------- in-place activation: y = relu(y*scale + shift) ----------------
template<int C>
__global__ void activate_kernel(float* __restrict__ y, const float* __restrict__ ss, int total)
{
    int i = (blockIdx.x * blockDim.x + threadIdx.x) * 4;
    if (i >= total) return;
    float4 v = *(const float4*)(y + i);
    const int c = i % C;
    v.x = fmaxf(v.x * ss[c + 0] + ss[C + c + 0], 0.f);
    v.y = fmaxf(v.y * ss[c + 1] + ss[C + c + 1], 0.f);
    v.z = fmaxf(v.z * ss[c + 2] + ss[C + c + 2], 0.f);
    v.w = fmaxf(v.w * ss[c + 3] + ss[C + c + 3], 0.f);
    *(float4*)(y + i) = v;
}

// ---------------- final write (activation into out) ----------------
__global__ void writeout_kernel(const float* __restrict__ y, const float* __restrict__ ss,
                                float* __restrict__ out, int total)
{
    int i = (blockIdx.x * blockDim.x + threadIdx.x) * 4;
    if (i >= total) return;
    float4 v = *(const float4*)(y + i);
    int c = i % 96;
    float4 o;
    o.x = fmaxf(v.x * ss[c + 0] + ss[96 + c + 0], 0.f);
    o.y = fmaxf(v.y * ss[c + 1] + ss[96 + c + 1], 0.f);
    o.z = fmaxf(v.z * ss[c + 2] + ss[96 + c + 2], 0.f);
    o.w = fmaxf(v.w * ss[c + 3] + ss[96 + c + 3], 0.f);
    *(float4*)(out + i) = o;
}

// ---------------- host ----------------
extern "C" void kernel_launch(void* const* d_in, const int* in_sizes, int n_in,
                              void* d_out, int out_size, void* d_ws, size_t ws_size,
                              hipStream_t stream)
{
    const float* data   = (const float*)d_in[0];
    const int*   neigh0 = (const int*)d_in[1];
    const int*   child0 = (const int*)d_in[2];
    const int*   neigh1 = (const int*)d_in[3];
    const int*   child1 = (const int*)d_in[4];
    const int*   neigh2 = (const int*)d_in[5];
    const float* w0  = (const float*)d_in[6];
    const float* g0  = (const float*)d_in[7];
    const float* b0  = (const float*)d_in[8];
    const float* wd0 = (const float*)d_in[9];
    const float* gd0 = (const float*)d_in[10];
    const float* bd0 = (const float*)d_in[11];
    const float* w1  = (const float*)d_in[12];
    const float* g1  = (const float*)d_in[13];
    const float* b1  = (const float*)d_in[14];
    const float* wd1 = (const float*)d_in[15];
    const float* gd1 = (const float*)d_in[16];
    const float* bd1 = (const float*)d_in[17];
    const float* wp  = (const float*)d_in[18];
    const float* gp  = (const float*)d_in[19];
    const float* bp  = (const float*)d_in[20];
    float* out = (float*)d_out;

    // header (floats)
    float* wsf = (float*)d_ws;
    int*   counters = (int*)d_ws;              // 5 ints in first 64B
    float* sums0 = wsf + 16;
    float* sums1 = wsf + 64;
    float* sums2 = wsf + 160;
    float* sums3 = wsf + 256;
    float* sums4 = wsf + 448;
    float* ss0 = wsf + 640;
    float* ss1 = wsf + 688;
    float* ss2 = wsf + 784;
    float* ss3 = wsf + 880;
    float* ss4 = wsf + 1072;                   // ends 1264, pad 1280

    // arena (same 59.8 MB footprint as round 3)
    float* x0 = wsf + 1280;                    // N0*24 = 6291456 (raw y0, then activated in place)
    float* y1 = x0 + (size_t)N0 * 24;          // N1*48 = 1572864
    float* y2 = y1 + (size_t)N1 * 48;          // 1572864
    float* y3 = y2 + (size_t)N1 * 48;          // N2*96 = 393216
    float* y4 = y3 + (size_t)N2 * 96;          // 393216
    float* pscratch = y4 + (size_t)N2 * 96;    // 4718592 floats (max partials: C uses 3*N1*48)

    // only counters + sums + ss need zeroing (5 KB)
    hipMemsetAsync(d_ws, 0, 1280 * sizeof(float), stream);

    const size_t s1 = (size_t)N1 * 48;  // partial stride, stages B/C
    const size_t s2 = (size_t)N2 * 96;  // partial stride, stages D/E

    // stage A: data[N0,3] -> x0 buffer (raw), then stats + in-place activation
    conv_kernel<27, 3, 24, 27, 24, 1, 1, true>
        <<<dim3(N0 / 256, 1, 1), 256, 0, stream>>>(data, neigh0, w0, x0, 0, N0);
    stats_kernel<24, 8, 1, false><<<512, dim3(24, 8), 0, stream>>>(x0, 0, nullptr, N0, g0, b0, sums0, &counters[0], ss0);
    activate_kernel<24><<<(N0 * 24 / 4 + 255) / 256, 256, 0, stream>>>(x0, ss0, N0 * 24);

    // stage B: x0 -> y1 (k-split 2 partials), stats sums partials -> y1, activate
    conv_kernel<8, 24, 48, 4, 24, 2, 2, false>
        <<<dim3(N1 / 256, 2, 2), 256, 0, stream>>>(x0, child0, wd0, pscratch, s1, N1);
    stats_kernel<48, 8, 2, true><<<128, dim3(48, 8), 0, stream>>>(pscratch, s1, y1, N1, gd0, bd0, sums1, &counters[1], ss1);
    activate_kernel<48><<<(N1 * 48 / 4 + 255) / 256, 256, 0, stream>>>(y1, ss1, N1 * 48);

    // stage C: y1(act) -> y2, k-split 3
    conv_kernel<27, 48, 48, 9, 24, 3, 2, false>
        <<<dim3(N1 / 256, 3, 2), 256, 0, stream>>>(y1, neigh1, w1, pscratch, s1, N1);
    stats_kernel<48, 8, 3, true><<<128, dim3(48, 8), 0, stream>>>(pscratch, s1, y2, N1, g1, b1, sums2, &counters[2], ss2);
    activate_kernel<48><<<(N1 * 48 / 4 + 255) / 256, 256, 0, stream>>>(y2, ss2, N1 * 48);

    // stage D: y2(act) -> y3, k-split 8
    conv_kernel<8, 48, 96, 1, 24, 8, 4, false>
        <<<dim3(N2 / 256, 8, 4), 256, 0, stream>>>(y2, child1, wd1, pscratch, s2, N2);
    stats_kernel<96, 4, 8, true><<<64, dim3(96, 4), 0, stream>>>(pscratch, s2, y3, N2, gd1, bd1, sums3, &counters[3], ss3);
    activate_kernel<96><<<(N2 * 96 / 4 + 255) / 256, 256, 0, stream>>>(y3, ss3, N2 * 96);

    // stage E: y3(act) -> y4, k-split 9 (TAPS=3, DG=4 for parallelism)
    conv_kernel<27, 96, 96, 3, 24, 9, 4, false>
        <<<dim3(N2 / 256, 9, 4), 256, 0, stream>>>(y3, neigh2, wp, pscratch, s2, N2);
    stats_kernel<96, 4, 9, true><<<64, dim3(96, 4), 0, stream>>>(pscratch, s2, y4, N2, gp, bp, sums4, &counters[4], ss4);

    // final normalize + relu -> out
    writeout_kernel<<<(N2 * 96 / 4 + 255) / 256, 256, 0, stream>>>(y4, ss4, out, N2 * 96);

    (void)in_sizes; (void)n_in; (void)out_size; (void)ws_size;
}